// Round 6
// baseline (380.139 us; speedup 1.0000x reference)
//
#include <hip/hip_runtime.h>

#define N_NODES 50000
#define NEG_SLOPE 0.2f

typedef short s8v __attribute__((ext_vector_type(8)));
typedef float f4v __attribute__((ext_vector_type(4)));

// ---- bf16 helpers (RNE) ---------------------------------------------------
__device__ __forceinline__ ushort f2bf(float f) {
  union { float f; unsigned u; } v; v.f = f;
  return (ushort)((v.u + 0x7FFFu + ((v.u >> 16) & 1u)) >> 16);
}
__device__ __forceinline__ float bf2f(ushort h) {
  union { unsigned u; float f; } v; v.u = ((unsigned)h) << 16;
  return v.f;
}

// ---- fp32 -> bf16 bulk convert (x) ----------------------------------------
__global__ void conv_x_kernel(const float* __restrict__ in, ushort* __restrict__ out, int n4) {
  int i = blockIdx.x * blockDim.x + threadIdx.x;
  if (i >= n4) return;
  float4 v = reinterpret_cast<const float4*>(in)[i];
  ushort4 o; o.x = f2bf(v.x); o.y = f2bf(v.y); o.z = f2bf(v.z); o.w = f2bf(v.w);
  reinterpret_cast<ushort4*>(out)[i] = o;
}

// ---- weight transpose+convert: in[R][C] fp32 -> out[C][R] bf16 ------------
__global__ void convT_kernel(const float* __restrict__ in, ushort* __restrict__ out,
                             int R, int C) {
  int i = blockIdx.x * blockDim.x + threadIdx.x;
  if (i >= R * C) return;
  int r = i / C, c = i % C;
  out[c * R + r] = f2bf(in[i]);
}

// ---- MFMA GEMM + fused attention scores -----------------------------------
template <int HEADS>
__global__ __launch_bounds__(256) void gemm_mfma(
    const ushort* __restrict__ A, const ushort* __restrict__ BT,
    ushort* __restrict__ C, int M, int N, int K,
    const float* __restrict__ a_src, const float* __restrict__ a_dst,
    float* __restrict__ ss, float* __restrict__ sd) {
  __shared__ ushort As[64][136];  // +8 pad: 16B-aligned, 2-way banks (free)
  __shared__ ushort Bs[64][136];
  const int tid = threadIdx.x;
  const int w = tid >> 6, lane = tid & 63;
  const int q = lane >> 4, r16 = lane & 15;
  const int m0 = blockIdx.x * 64, n0 = blockIdx.y * 64;
  f4v acc[4] = {};
  for (int kc = 0; kc < K; kc += 128) {
#pragma unroll
    for (int i = 0; i < 4; ++i) {
      int c = tid + 256 * i;
      int row = c >> 4, ko = (c & 15) * 8;
      int gm = m0 + row;
      s8v va = {};
      if (gm < M) va = *reinterpret_cast<const s8v*>(&A[(size_t)gm * K + kc + ko]);
      *reinterpret_cast<s8v*>(&As[row][ko]) = va;
      s8v vb = *reinterpret_cast<const s8v*>(&BT[(size_t)(n0 + row) * K + kc + ko]);
      *reinterpret_cast<s8v*>(&Bs[row][ko]) = vb;
    }
    __syncthreads();
#pragma unroll
    for (int ks = 0; ks < 4; ++ks) {
      s8v af = *reinterpret_cast<const s8v*>(&As[w * 16 + r16][ks * 32 + q * 8]);
#pragma unroll
      for (int nt = 0; nt < 4; ++nt) {
        s8v bf = *reinterpret_cast<const s8v*>(&Bs[nt * 16 + r16][ks * 32 + q * 8]);
        acc[nt] = __builtin_amdgcn_mfma_f32_16x16x32_bf16(af, bf, acc[nt], 0, 0, 0);
      }
    }
    __syncthreads();
  }
  // C store: D row=(lane>>4)*4+reg, col=lane&15
#pragma unroll
  for (int nt = 0; nt < 4; ++nt)
#pragma unroll
    for (int r = 0; r < 4; ++r) {
      int gm = m0 + w * 16 + q * 4 + r;
      if (gm < M) C[(size_t)gm * N + n0 + nt * 16 + r16] = f2bf(acc[nt][r]);
    }
  // fused scores epilogue (head uniform per block: n-tile 64-wide, heads 128-aligned)
  const int head = n0 >> 7;
  float ps[4] = {0.f, 0.f, 0.f, 0.f}, pd[4] = {0.f, 0.f, 0.f, 0.f};
#pragma unroll
  for (int nt = 0; nt < 4; ++nt) {
    int n = n0 + nt * 16 + r16;
    float as = a_src[n], ad = a_dst[n];
#pragma unroll
    for (int r = 0; r < 4; ++r) {
      ps[r] = fmaf(acc[nt][r], as, ps[r]);
      pd[r] = fmaf(acc[nt][r], ad, pd[r]);
    }
  }
#pragma unroll
  for (int off = 1; off < 16; off <<= 1) {
#pragma unroll
    for (int r = 0; r < 4; ++r) {
      ps[r] += __shfl_xor(ps[r], off);
      pd[r] += __shfl_xor(pd[r], off);
    }
  }
  if (r16 == 0) {
#pragma unroll
    for (int r = 0; r < 4; ++r) {
      int gm = m0 + w * 16 + q * 4 + r;
      if (gm < M) {
        atomicAdd(&ss[gm * HEADS + head], ps[r]);
        atomicAdd(&sd[gm * HEADS + head], pd[r]);
      }
    }
  }
}

// ------------- CSR build: hist(+rank) -> 3-pass scan -> scatter -------------
__global__ void hist_kernel(const int* __restrict__ ei, int E, int Etot,
                            int* __restrict__ counts, int* __restrict__ rank) {
  int e = blockIdx.x * blockDim.x + threadIdx.x;
  if (e >= Etot) return;
  int d = (e < E) ? ei[E + e] : (e - E);
  rank[e] = atomicAdd(&counts[d], 1);
}

__global__ __launch_bounds__(1024) void scan1_kernel(const int* __restrict__ counts,
                                                     int* __restrict__ partial,
                                                     int* __restrict__ blocksums, int n) {
  __shared__ int tmp[1024];
  int i = blockIdx.x * 1024 + threadIdx.x;
  int v = (i < n) ? counts[i] : 0;
  tmp[threadIdx.x] = v;
  __syncthreads();
  for (int off = 1; off < 1024; off <<= 1) {
    int t = (threadIdx.x >= off) ? tmp[threadIdx.x - off] : 0;
    __syncthreads();
    tmp[threadIdx.x] += t;
    __syncthreads();
  }
  if (i < n) partial[i] = tmp[threadIdx.x];
  if (threadIdx.x == 1023) blocksums[blockIdx.x] = tmp[1023];
}

__global__ __launch_bounds__(64) void scan2_kernel(int* __restrict__ blocksums, int nb) {
  int t = threadIdx.x;
  int v = (t < nb) ? blocksums[t] : 0;
#pragma unroll
  for (int off = 1; off < 64; off <<= 1) {
    int u = __shfl_up(v, off);
    if (t >= off) v += u;
  }
  if (t < nb) blocksums[t] = v;
}

__global__ void scan3_kernel(const int* __restrict__ partial,
                             const int* __restrict__ blocksums,
                             int* __restrict__ rowptr, int n) {
  int i = blockIdx.x * blockDim.x + threadIdx.x;
  if (i == 0) rowptr[0] = 0;
  if (i < n) {
    int b = i >> 10;
    int add = (b > 0) ? blocksums[b - 1] : 0;
    rowptr[i + 1] = partial[i] + add;
  }
}

// scatter: no atomics; one 8B packed write per edge (one random line touch)
__global__ void scatter_kernel(const int* __restrict__ ei, int E, int Etot,
                               const int* __restrict__ rowptr,
                               const int* __restrict__ rank,
                               unsigned long long* __restrict__ csr) {
  int e = blockIdx.x * blockDim.x + threadIdx.x;
  if (e >= Etot) return;
  int s, d;
  if (e < E) { s = ei[e]; d = ei[E + e]; } else { s = d = e - E; }
  int pos = rowptr[d] + rank[e];
  csr[pos] = ((unsigned long long)(unsigned)d << 32) | (unsigned)s;
}

// ---- edge weights layer 0: bf16 w + u16 src side-array (all sequential) ----
__global__ void ew0_kernel(const uint2* __restrict__ csr,
                           const float* __restrict__ ss, const float* __restrict__ sd,
                           ushort* __restrict__ wbf, ushort* __restrict__ csrS, int Etot) {
  int p = blockIdx.x * blockDim.x + threadIdx.x;
  if (p >= Etot) return;
  uint2 e2 = csr[p];
  int s = (int)e2.x, d = (int)e2.y;
  csrS[p] = (ushort)s;  // src < 50000 < 65536
  ushort2 o;
  {
    float e = ss[s * 2 + 0] + sd[d * 2 + 0];
    e = (e > 0.f) ? e : NEG_SLOPE * e;
    o.x = f2bf(__expf(e));
  }
  {
    float e = ss[s * 2 + 1] + sd[d * 2 + 1];
    e = (e > 0.f) ? e : NEG_SLOPE * e;
    o.y = f2bf(__expf(e));
  }
  *reinterpret_cast<ushort2*>(&wbf[p * 2]) = o;
}

// ---- edge weights layer 1 --------------------------------------------------
__global__ void ew1_kernel(const uint2* __restrict__ csr,
                           const float* __restrict__ ss, const float* __restrict__ sd,
                           ushort* __restrict__ wbf, int Etot) {
  int p = blockIdx.x * blockDim.x + threadIdx.x;
  if (p >= Etot) return;
  uint2 e2 = csr[p];
  int s = (int)e2.x, d = (int)e2.y;
  float e = ss[s] + sd[d];
  e = (e > 0.f) ? e : NEG_SLOPE * e;
  wbf[p] = f2bf(__expf(e));
}

// ---- layer-0 aggregation, XCD-sliced --------------------------------------
// slice = bid&7 -> XCD via round-robin dispatch; per-XCD gather working set
// = 50000 rows x 64B slice = 3.2 MB < 4 MB L2. Block: 16 dst x 4 lanes,
// 16B/lane. Per-lane divergent edge loop (masked).
__global__ __launch_bounds__(64) void agg0_kernel(
    const ushort* __restrict__ h0,   // [N,256] bf16
    const ushort* __restrict__ wbf,  // [Etot,2] bf16
    const int* __restrict__ rowptr, const ushort* __restrict__ csrS,
    const float* __restrict__ b0, ushort* __restrict__ hE) {
  const int bid = blockIdx.x;          // 25000 = 3125 * 8
  const int slice = bid & 7;
  const int n = (bid >> 3) * 16 + (threadIdx.x >> 2);
  const int c = threadIdx.x & 3;
  const int head = slice >> 2;
  const int choff = slice * 32 + c * 8;
  int p = rowptr[n];
  const int p1 = rowptr[n + 1];
  float acc[8] = {};
  float den = 0.f;
  while (__any(p < p1)) {
    if (p < p1) {
      const int s = csrS[p];
      const float w = bf2f(wbf[p * 2 + head]);
      s8v v = *reinterpret_cast<const s8v*>(&h0[(size_t)s * 256 + choff]);
      den += w;
#pragma unroll
      for (int j = 0; j < 8; ++j) acc[j] = fmaf(w, bf2f((ushort)v[j]), acc[j]);
      ++p;
    }
  }
  const float inv = 1.f / den;
  const float4 bA = *reinterpret_cast<const float4*>(&b0[choff]);
  const float4 bB = *reinterpret_cast<const float4*>(&b0[choff + 4]);
  float o[8] = {fmaf(acc[0], inv, bA.x), fmaf(acc[1], inv, bA.y),
                fmaf(acc[2], inv, bA.z), fmaf(acc[3], inv, bA.w),
                fmaf(acc[4], inv, bB.x), fmaf(acc[5], inv, bB.y),
                fmaf(acc[6], inv, bB.z), fmaf(acc[7], inv, bB.w)};
  s8v ov;
#pragma unroll
  for (int j = 0; j < 8; ++j) {
    float e = (o[j] > 0.f) ? o[j] : (__expf(o[j]) - 1.f);
    ov[j] = (short)f2bf(e);
  }
  *reinterpret_cast<s8v*>(&hE[(size_t)n * 256 + choff]) = ov;
}

// ---- layer-1 aggregation, XCD-sliced (4 slices x 64B) + bias + residual ----
__global__ __launch_bounds__(64) void agg1_kernel(
    const ushort* __restrict__ h1,   // [N,128] bf16
    const ushort* __restrict__ wbf,  // [Etot] bf16
    const int* __restrict__ rowptr, const ushort* __restrict__ csrS,
    const float* __restrict__ b1, const float* __restrict__ x,
    float* __restrict__ out) {
  const int bid = blockIdx.x;          // 12500 = 3125 * 4
  const int slice = bid & 3;
  const int n = (bid >> 2) * 16 + (threadIdx.x >> 2);
  const int c = threadIdx.x & 3;
  const int choff = slice * 32 + c * 8;
  int p = rowptr[n];
  const int p1 = rowptr[n + 1];
  float acc[8] = {};
  float den = 0.f;
  while (__any(p < p1)) {
    if (p < p1) {
      const int s = csrS[p];
      const float w = bf2f(wbf[p]);
      s8v v = *reinterpret_cast<const s8v*>(&h1[(size_t)s * 128 + choff]);
      den += w;
#pragma unroll
      for (int j = 0; j < 8; ++j) acc[j] = fmaf(w, bf2f((ushort)v[j]), acc[j]);
      ++p;
    }
  }
  const float inv = 1.f / den;
  const float4 bA = *reinterpret_cast<const float4*>(&b1[choff]);
  const float4 bB = *reinterpret_cast<const float4*>(&b1[choff + 4]);
  const float4 xA = *reinterpret_cast<const float4*>(&x[(size_t)n * 128 + choff]);
  const float4 xB = *reinterpret_cast<const float4*>(&x[(size_t)n * 128 + choff + 4]);
  float4 oA, oB;
  oA.x = xA.x + fmaf(acc[0], inv, bA.x);
  oA.y = xA.y + fmaf(acc[1], inv, bA.y);
  oA.z = xA.z + fmaf(acc[2], inv, bA.z);
  oA.w = xA.w + fmaf(acc[3], inv, bA.w);
  oB.x = xB.x + fmaf(acc[4], inv, bB.x);
  oB.y = xB.y + fmaf(acc[5], inv, bB.y);
  oB.z = xB.z + fmaf(acc[6], inv, bB.z);
  oB.w = xB.w + fmaf(acc[7], inv, bB.w);
  *reinterpret_cast<float4*>(&out[(size_t)n * 128 + choff]) = oA;
  *reinterpret_cast<float4*>(&out[(size_t)n * 128 + choff + 4]) = oB;
}

extern "C" void kernel_launch(void* const* d_in, const int* in_sizes, int n_in,
                              void* d_out, int out_size, void* d_ws, size_t ws_size,
                              hipStream_t stream) {
  const float* x      = (const float*)d_in[0];
  const float* W0     = (const float*)d_in[1];
  const float* a_src0 = (const float*)d_in[2];
  const float* a_dst0 = (const float*)d_in[3];
  const float* b0     = (const float*)d_in[4];
  const float* W1     = (const float*)d_in[5];
  const float* a_src1 = (const float*)d_in[6];
  const float* a_dst1 = (const float*)d_in[7];
  const float* b1     = (const float*)d_in[8];
  const int*   ei     = (const int*)d_in[9];
  const int E = in_sizes[9] / 2;
  const int Etot = E + N_NODES;
  float* out = (float*)d_out;
  (void)n_in; (void)out_size; (void)ws_size;

  char* ws = (char*)d_ws;
  size_t off = 0;
  auto alloc = [&](size_t bytes) -> char* {
    char* p = ws + off;
    off += (bytes + 255) & ~(size_t)255;
    return p;
  };
  ushort* xb   = (ushort*)alloc((size_t)N_NODES * 128 * 2);
  ushort* h0b  = (ushort*)alloc((size_t)N_NODES * 256 * 2);
  ushort* hEb  = (ushort*)alloc((size_t)N_NODES * 256 * 2);
  ushort* h1b  = (ushort*)alloc((size_t)N_NODES * 128 * 2);
  ushort* W0T  = (ushort*)alloc((size_t)256 * 128 * 2);
  ushort* W1T  = (ushort*)alloc((size_t)128 * 256 * 2);
  // ---- contiguous zero-init region: [counts, ss0, sd0, ss1, sd1] ----------
  size_t zoff0 = off;
  int* counts  = (int*)alloc((size_t)N_NODES * 4);
  float* ss0   = (float*)alloc((size_t)N_NODES * 2 * 4);
  float* sd0   = (float*)alloc((size_t)N_NODES * 2 * 4);
  float* ss1   = (float*)alloc((size_t)N_NODES * 4);
  float* sd1   = (float*)alloc((size_t)N_NODES * 4);
  size_t zbytes = off - zoff0;
  int* rowptr  = (int*)alloc((size_t)(N_NODES + 1) * 4);
  int* partial = (int*)alloc((size_t)N_NODES * 4);
  int* bsums   = (int*)alloc((size_t)64 * 4);
  int* rank    = (int*)alloc((size_t)Etot * 4);
  unsigned long long* csr = (unsigned long long*)alloc((size_t)Etot * 8);
  ushort* wbf0 = (ushort*)alloc((size_t)Etot * 2 * 2);
  ushort* wbf1 = (ushort*)alloc((size_t)Etot * 2);
  ushort* csrS = (ushort*)alloc((size_t)Etot * 2);

  hipMemsetAsync(ws + zoff0, 0, zbytes, stream);

  // ---- prep: bf16 conversions ----
  int n4 = N_NODES * 128 / 4;
  conv_x_kernel<<<(n4 + 255) / 256, 256, 0, stream>>>(x, xb, n4);
  convT_kernel<<<(128 * 256 + 255) / 256, 256, 0, stream>>>(W0, W0T, 128, 256);
  convT_kernel<<<(256 * 128 + 255) / 256, 256, 0, stream>>>(W1, W1T, 256, 128);

  // ---- CSR build (shared by both layers) ----
  const int nblk = (N_NODES + 1023) / 1024;  // 49
  hist_kernel<<<(Etot + 255) / 256, 256, 0, stream>>>(ei, E, Etot, counts, rank);
  scan1_kernel<<<nblk, 1024, 0, stream>>>(counts, partial, bsums, N_NODES);
  scan2_kernel<<<1, 64, 0, stream>>>(bsums, nblk);
  scan3_kernel<<<(N_NODES + 255) / 256, 256, 0, stream>>>(partial, bsums, rowptr, N_NODES);
  scatter_kernel<<<(Etot + 255) / 256, 256, 0, stream>>>(ei, E, Etot, rowptr, rank, csr);

  // ---- layer 0 ----
  dim3 g0((N_NODES + 63) / 64, 256 / 64);
  gemm_mfma<2><<<g0, 256, 0, stream>>>(xb, W0T, h0b, N_NODES, 256, 128,
                                       a_src0, a_dst0, ss0, sd0);
  ew0_kernel<<<(Etot + 255) / 256, 256, 0, stream>>>((const uint2*)csr, ss0, sd0,
                                                     wbf0, csrS, Etot);
  agg0_kernel<<<(N_NODES / 16) * 8, 64, 0, stream>>>(h0b, wbf0, rowptr, csrS, b0, hEb);

  // ---- layer 1 ----
  dim3 g1((N_NODES + 63) / 64, 128 / 64);
  gemm_mfma<1><<<g1, 256, 0, stream>>>(hEb, W1T, h1b, N_NODES, 128, 256,
                                       a_src1, a_dst1, ss1, sd1);
  ew1_kernel<<<(Etot + 255) / 256, 256, 0, stream>>>((const uint2*)csr, ss1, sd1,
                                                     wbf1, Etot);
  agg1_kernel<<<(N_NODES / 16) * 4, 64, 0, stream>>>(h1b, wbf1, rowptr, csrS, b1,
                                                     x, out);
}

// Round 7
// 312.230 us; speedup vs baseline: 1.2175x; 1.2175x over previous
//
#include <hip/hip_runtime.h>

#define N_NODES 50000
#define NEG_SLOPE 0.2f

typedef short s8v __attribute__((ext_vector_type(8)));
typedef float f4v __attribute__((ext_vector_type(4)));

// ---- bf16 helpers (RNE) ---------------------------------------------------
__device__ __forceinline__ ushort f2bf(float f) {
  union { float f; unsigned u; } v; v.f = f;
  return (ushort)((v.u + 0x7FFFu + ((v.u >> 16) & 1u)) >> 16);
}
__device__ __forceinline__ float bf2f(ushort h) {
  union { unsigned u; float f; } v; v.u = ((unsigned)h) << 16;
  return v.f;
}

// ---- weight transpose+convert: in[R][C] fp32 -> out[C][R] bf16 ------------
__global__ void convT_kernel(const float* __restrict__ in, ushort* __restrict__ out,
                             int R, int C) {
  int i = blockIdx.x * blockDim.x + threadIdx.x;
  if (i >= R * C) return;
  int r = i / C, c = i % C;
  out[c * R + r] = f2bf(in[i]);
}

// ---- MFMA GEMM + fused attention scores -----------------------------------
// A: fp32 (AF32=true, converted during staging) or bf16. BT: bf16 [N,K].
// 64x64 tile, BK=128. Epilogue: ss/sd[m,head] += <C_row, a_src/a_dst>.
template <int HEADS, bool AF32>
__global__ __launch_bounds__(256) void gemm_mfma(
    const void* __restrict__ Av, const ushort* __restrict__ BT,
    ushort* __restrict__ C, int M, int N, int K,
    const float* __restrict__ a_src, const float* __restrict__ a_dst,
    float* __restrict__ ss, float* __restrict__ sd) {
  __shared__ ushort As[64][136];  // +8 pad: 16B-aligned, 2-way banks (free)
  __shared__ ushort Bs[64][136];
  const int tid = threadIdx.x;
  const int w = tid >> 6, lane = tid & 63;
  const int q = lane >> 4, r16 = lane & 15;
  const int m0 = blockIdx.x * 64, n0 = blockIdx.y * 64;
  f4v acc[4] = {};
  for (int kc = 0; kc < K; kc += 128) {
#pragma unroll
    for (int i = 0; i < 4; ++i) {
      int c = tid + 256 * i;
      int row = c >> 4, ko = (c & 15) * 8;
      int gm = m0 + row;
      s8v va = {};
      if (gm < M) {
        if (AF32) {
          const float* A = (const float*)Av;
          float4 f0 = *reinterpret_cast<const float4*>(&A[(size_t)gm * K + kc + ko]);
          float4 f1 = *reinterpret_cast<const float4*>(&A[(size_t)gm * K + kc + ko + 4]);
          va[0] = (short)f2bf(f0.x); va[1] = (short)f2bf(f0.y);
          va[2] = (short)f2bf(f0.z); va[3] = (short)f2bf(f0.w);
          va[4] = (short)f2bf(f1.x); va[5] = (short)f2bf(f1.y);
          va[6] = (short)f2bf(f1.z); va[7] = (short)f2bf(f1.w);
        } else {
          const ushort* A = (const ushort*)Av;
          va = *reinterpret_cast<const s8v*>(&A[(size_t)gm * K + kc + ko]);
        }
      }
      *reinterpret_cast<s8v*>(&As[row][ko]) = va;
      s8v vb = *reinterpret_cast<const s8v*>(&BT[(size_t)(n0 + row) * K + kc + ko]);
      *reinterpret_cast<s8v*>(&Bs[row][ko]) = vb;
    }
    __syncthreads();
#pragma unroll
    for (int ks = 0; ks < 4; ++ks) {
      s8v af = *reinterpret_cast<const s8v*>(&As[w * 16 + r16][ks * 32 + q * 8]);
#pragma unroll
      for (int nt = 0; nt < 4; ++nt) {
        s8v bf = *reinterpret_cast<const s8v*>(&Bs[nt * 16 + r16][ks * 32 + q * 8]);
        acc[nt] = __builtin_amdgcn_mfma_f32_16x16x32_bf16(af, bf, acc[nt], 0, 0, 0);
      }
    }
    __syncthreads();
  }
  // C store: D row=(lane>>4)*4+reg, col=lane&15
#pragma unroll
  for (int nt = 0; nt < 4; ++nt)
#pragma unroll
    for (int r = 0; r < 4; ++r) {
      int gm = m0 + w * 16 + q * 4 + r;
      if (gm < M) C[(size_t)gm * N + n0 + nt * 16 + r16] = f2bf(acc[nt][r]);
    }
  // fused scores epilogue (head uniform per block: n-tile 64-wide, heads 128-aligned)
  const int head = n0 >> 7;
  float ps[4] = {0.f, 0.f, 0.f, 0.f}, pd[4] = {0.f, 0.f, 0.f, 0.f};
#pragma unroll
  for (int nt = 0; nt < 4; ++nt) {
    int n = n0 + nt * 16 + r16;
    float as = a_src[n], ad = a_dst[n];
#pragma unroll
    for (int r = 0; r < 4; ++r) {
      ps[r] = fmaf(acc[nt][r], as, ps[r]);
      pd[r] = fmaf(acc[nt][r], ad, pd[r]);
    }
  }
#pragma unroll
  for (int off = 1; off < 16; off <<= 1) {
#pragma unroll
    for (int r = 0; r < 4; ++r) {
      ps[r] += __shfl_xor(ps[r], off);
      pd[r] += __shfl_xor(pd[r], off);
    }
  }
  if (r16 == 0) {
#pragma unroll
    for (int r = 0; r < 4; ++r) {
      int gm = m0 + w * 16 + q * 4 + r;
      if (gm < M) {
        atomicAdd(&ss[gm * HEADS + head], ps[r]);
        atomicAdd(&sd[gm * HEADS + head], pd[r]);
      }
    }
  }
}

// ------------- CSR build: hist(+rank) -> 3-pass scan -> scatter -------------
__global__ void hist_kernel(const int* __restrict__ ei, int E, int Etot,
                            int* __restrict__ counts, int* __restrict__ rank) {
  int e = blockIdx.x * blockDim.x + threadIdx.x;
  if (e >= Etot) return;
  int d = (e < E) ? ei[E + e] : (e - E);
  rank[e] = atomicAdd(&counts[d], 1);
}

__global__ __launch_bounds__(1024) void scan1_kernel(const int* __restrict__ counts,
                                                     int* __restrict__ partial,
                                                     int* __restrict__ blocksums, int n) {
  __shared__ int tmp[1024];
  int i = blockIdx.x * 1024 + threadIdx.x;
  int v = (i < n) ? counts[i] : 0;
  tmp[threadIdx.x] = v;
  __syncthreads();
  for (int off = 1; off < 1024; off <<= 1) {
    int t = (threadIdx.x >= off) ? tmp[threadIdx.x - off] : 0;
    __syncthreads();
    tmp[threadIdx.x] += t;
    __syncthreads();
  }
  if (i < n) partial[i] = tmp[threadIdx.x];
  if (threadIdx.x == 1023) blocksums[blockIdx.x] = tmp[1023];
}

__global__ __launch_bounds__(64) void scan2_kernel(int* __restrict__ blocksums, int nb) {
  int t = threadIdx.x;
  int v = (t < nb) ? blocksums[t] : 0;
#pragma unroll
  for (int off = 1; off < 64; off <<= 1) {
    int u = __shfl_up(v, off);
    if (t >= off) v += u;
  }
  if (t < nb) blocksums[t] = v;
}

__global__ void scan3_kernel(const int* __restrict__ partial,
                             const int* __restrict__ blocksums,
                             int* __restrict__ rowptr, int n) {
  int i = blockIdx.x * blockDim.x + threadIdx.x;
  if (i == 0) rowptr[0] = 0;
  if (i < n) {
    int b = i >> 10;
    int add = (b > 0) ? blocksums[b - 1] : 0;
    rowptr[i + 1] = partial[i] + add;
  }
}

// scatter: no atomics; one 8B packed write per edge (one random line touch)
__global__ void scatter_kernel(const int* __restrict__ ei, int E, int Etot,
                               const int* __restrict__ rowptr,
                               const int* __restrict__ rank,
                               unsigned long long* __restrict__ csr) {
  int e = blockIdx.x * blockDim.x + threadIdx.x;
  if (e >= Etot) return;
  int s, d;
  if (e < E) { s = ei[e]; d = ei[E + e]; } else { s = d = e - E; }
  int pos = rowptr[d] + rank[e];
  csr[pos] = ((unsigned long long)(unsigned)d << 32) | (unsigned)s;
}

// ---- edge weights layer 0: bf16 w + u16 src side-array (all sequential) ----
__global__ void ew0_kernel(const uint2* __restrict__ csr,
                           const float* __restrict__ ss, const float* __restrict__ sd,
                           ushort* __restrict__ wbf, ushort* __restrict__ csrS, int Etot) {
  int p = blockIdx.x * blockDim.x + threadIdx.x;
  if (p >= Etot) return;
  uint2 e2 = csr[p];
  int s = (int)e2.x, d = (int)e2.y;
  csrS[p] = (ushort)s;  // src < 50000 < 65536
  ushort2 o;
  {
    float e = ss[s * 2 + 0] + sd[d * 2 + 0];
    e = (e > 0.f) ? e : NEG_SLOPE * e;
    o.x = f2bf(__expf(e));
  }
  {
    float e = ss[s * 2 + 1] + sd[d * 2 + 1];
    e = (e > 0.f) ? e : NEG_SLOPE * e;
    o.y = f2bf(__expf(e));
  }
  *reinterpret_cast<ushort2*>(&wbf[p * 2]) = o;
}

__global__ void ew1_kernel(const uint2* __restrict__ csr,
                           const float* __restrict__ ss, const float* __restrict__ sd,
                           ushort* __restrict__ wbf, int Etot) {
  int p = blockIdx.x * blockDim.x + threadIdx.x;
  if (p >= Etot) return;
  uint2 e2 = csr[p];
  int s = (int)e2.x, d = (int)e2.y;
  float e = ss[s] + sd[d];
  e = (e > 0.f) ? e : NEG_SLOPE * e;
  wbf[p] = f2bf(__expf(e));
}

// ---- layer-0 aggregation: 4 waves/block, one dst-node per wave ------------
__global__ __launch_bounds__(256) void agg0_kernel(
    const ushort* __restrict__ h0,   // [N,256] bf16
    const ushort* __restrict__ wbf,  // [Etot,2] bf16
    const int* __restrict__ rowptr, const ushort* __restrict__ csrS,
    const float* __restrict__ b0, ushort* __restrict__ hE) {
  const int n = blockIdx.x * 4 + (threadIdx.x >> 6);
  const int t = threadIdx.x & 63;
  const int hd = t >> 5;
  float a0 = 0.f, a1 = 0.f, a2 = 0.f, a3 = 0.f, den = 0.f;
  int p = rowptr[n];
  const int p1 = rowptr[n + 1];
  for (; p + 4 <= p1; p += 4) {  // 4 rows in flight per wave
    const int s0 = csrS[p], s1 = csrS[p + 1], s2 = csrS[p + 2], s3 = csrS[p + 3];
    const float w0 = bf2f(wbf[p * 2 + hd]),     w1 = bf2f(wbf[p * 2 + 2 + hd]);
    const float w2 = bf2f(wbf[p * 2 + 4 + hd]), w3 = bf2f(wbf[p * 2 + 6 + hd]);
    const ushort4 v0 = *reinterpret_cast<const ushort4*>(&h0[(size_t)s0 * 256 + t * 4]);
    const ushort4 v1 = *reinterpret_cast<const ushort4*>(&h0[(size_t)s1 * 256 + t * 4]);
    const ushort4 v2 = *reinterpret_cast<const ushort4*>(&h0[(size_t)s2 * 256 + t * 4]);
    const ushort4 v3 = *reinterpret_cast<const ushort4*>(&h0[(size_t)s3 * 256 + t * 4]);
    den += (w0 + w1) + (w2 + w3);
    a0 = fmaf(w0, bf2f(v0.x), a0); a1 = fmaf(w0, bf2f(v0.y), a1);
    a2 = fmaf(w0, bf2f(v0.z), a2); a3 = fmaf(w0, bf2f(v0.w), a3);
    a0 = fmaf(w1, bf2f(v1.x), a0); a1 = fmaf(w1, bf2f(v1.y), a1);
    a2 = fmaf(w1, bf2f(v1.z), a2); a3 = fmaf(w1, bf2f(v1.w), a3);
    a0 = fmaf(w2, bf2f(v2.x), a0); a1 = fmaf(w2, bf2f(v2.y), a1);
    a2 = fmaf(w2, bf2f(v2.z), a2); a3 = fmaf(w2, bf2f(v2.w), a3);
    a0 = fmaf(w3, bf2f(v3.x), a0); a1 = fmaf(w3, bf2f(v3.y), a1);
    a2 = fmaf(w3, bf2f(v3.z), a2); a3 = fmaf(w3, bf2f(v3.w), a3);
  }
  for (; p < p1; ++p) {
    const int s0 = csrS[p];
    const float w0 = bf2f(wbf[p * 2 + hd]);
    const ushort4 v0 = *reinterpret_cast<const ushort4*>(&h0[(size_t)s0 * 256 + t * 4]);
    den += w0;
    a0 = fmaf(w0, bf2f(v0.x), a0); a1 = fmaf(w0, bf2f(v0.y), a1);
    a2 = fmaf(w0, bf2f(v0.z), a2); a3 = fmaf(w0, bf2f(v0.w), a3);
  }
  const float inv = 1.f / den;
  const float4 bv = reinterpret_cast<const float4*>(b0)[t];
  float o[4] = {fmaf(a0, inv, bv.x), fmaf(a1, inv, bv.y),
                fmaf(a2, inv, bv.z), fmaf(a3, inv, bv.w)};
#pragma unroll
  for (int i = 0; i < 4; ++i) o[i] = (o[i] > 0.f) ? o[i] : (__expf(o[i]) - 1.f);
  ushort4 ov; ov.x = f2bf(o[0]); ov.y = f2bf(o[1]); ov.z = f2bf(o[2]); ov.w = f2bf(o[3]);
  *reinterpret_cast<ushort4*>(&hE[(size_t)n * 256 + t * 4]) = ov;
}

// ---- layer-1 aggregation: 4 waves/block, one dst-node per wave ------------
__global__ __launch_bounds__(256) void agg1_kernel(
    const ushort* __restrict__ h1,   // [N,128] bf16
    const ushort* __restrict__ wbf,  // [Etot] bf16
    const int* __restrict__ rowptr, const ushort* __restrict__ csrS,
    const float* __restrict__ b1, const float2* __restrict__ x,
    float2* __restrict__ out) {
  const int n = blockIdx.x * 4 + (threadIdx.x >> 6);
  const int t = threadIdx.x & 63;
  float a0 = 0.f, a1 = 0.f, den = 0.f;
  int p = rowptr[n];
  const int p1 = rowptr[n + 1];
  for (; p + 4 <= p1; p += 4) {
    const int s0 = csrS[p], s1 = csrS[p + 1], s2 = csrS[p + 2], s3 = csrS[p + 3];
    const float w0 = bf2f(wbf[p]), w1 = bf2f(wbf[p + 1]);
    const float w2 = bf2f(wbf[p + 2]), w3 = bf2f(wbf[p + 3]);
    const ushort2 v0 = *reinterpret_cast<const ushort2*>(&h1[(size_t)s0 * 128 + t * 2]);
    const ushort2 v1 = *reinterpret_cast<const ushort2*>(&h1[(size_t)s1 * 128 + t * 2]);
    const ushort2 v2 = *reinterpret_cast<const ushort2*>(&h1[(size_t)s2 * 128 + t * 2]);
    const ushort2 v3 = *reinterpret_cast<const ushort2*>(&h1[(size_t)s3 * 128 + t * 2]);
    den += (w0 + w1) + (w2 + w3);
    a0 = fmaf(w0, bf2f(v0.x), a0); a1 = fmaf(w0, bf2f(v0.y), a1);
    a0 = fmaf(w1, bf2f(v1.x), a0); a1 = fmaf(w1, bf2f(v1.y), a1);
    a0 = fmaf(w2, bf2f(v2.x), a0); a1 = fmaf(w2, bf2f(v2.y), a1);
    a0 = fmaf(w3, bf2f(v3.x), a0); a1 = fmaf(w3, bf2f(v3.y), a1);
  }
  for (; p < p1; ++p) {
    const int s0 = csrS[p];
    const float w0 = bf2f(wbf[p]);
    const ushort2 v0 = *reinterpret_cast<const ushort2*>(&h1[(size_t)s0 * 128 + t * 2]);
    den += w0;
    a0 = fmaf(w0, bf2f(v0.x), a0); a1 = fmaf(w0, bf2f(v0.y), a1);
  }
  const float inv = 1.f / den;
  const float2 bv = reinterpret_cast<const float2*>(b1)[t];
  const float2 xv = x[(size_t)n * 64 + t];
  out[(size_t)n * 64 + t] =
      make_float2(xv.x + fmaf(a0, inv, bv.x), xv.y + fmaf(a1, inv, bv.y));
}

extern "C" void kernel_launch(void* const* d_in, const int* in_sizes, int n_in,
                              void* d_out, int out_size, void* d_ws, size_t ws_size,
                              hipStream_t stream) {
  const float* x      = (const float*)d_in[0];
  const float* W0     = (const float*)d_in[1];
  const float* a_src0 = (const float*)d_in[2];
  const float* a_dst0 = (const float*)d_in[3];
  const float* b0     = (const float*)d_in[4];
  const float* W1     = (const float*)d_in[5];
  const float* a_src1 = (const float*)d_in[6];
  const float* a_dst1 = (const float*)d_in[7];
  const float* b1     = (const float*)d_in[8];
  const int*   ei     = (const int*)d_in[9];
  const int E = in_sizes[9] / 2;
  const int Etot = E + N_NODES;
  float* out = (float*)d_out;
  (void)n_in; (void)out_size; (void)ws_size;

  char* ws = (char*)d_ws;
  size_t off = 0;
  auto alloc = [&](size_t bytes) -> char* {
    char* p = ws + off;
    off += (bytes + 255) & ~(size_t)255;
    return p;
  };
  ushort* h0b  = (ushort*)alloc((size_t)N_NODES * 256 * 2);
  ushort* hEb  = (ushort*)alloc((size_t)N_NODES * 256 * 2);
  ushort* h1b  = (ushort*)alloc((size_t)N_NODES * 128 * 2);
  ushort* W0T  = (ushort*)alloc((size_t)256 * 128 * 2);
  ushort* W1T  = (ushort*)alloc((size_t)128 * 256 * 2);
  // ---- contiguous zero-init region: [counts, ss0, sd0, ss1, sd1] ----------
  size_t zoff0 = off;
  int* counts  = (int*)alloc((size_t)N_NODES * 4);
  float* ss0   = (float*)alloc((size_t)N_NODES * 2 * 4);
  float* sd0   = (float*)alloc((size_t)N_NODES * 2 * 4);
  float* ss1   = (float*)alloc((size_t)N_NODES * 4);
  float* sd1   = (float*)alloc((size_t)N_NODES * 4);
  size_t zbytes = off - zoff0;
  int* rowptr  = (int*)alloc((size_t)(N_NODES + 1) * 4);
  int* partial = (int*)alloc((size_t)N_NODES * 4);
  int* bsums   = (int*)alloc((size_t)64 * 4);
  int* rank    = (int*)alloc((size_t)Etot * 4);
  unsigned long long* csr = (unsigned long long*)alloc((size_t)Etot * 8);
  ushort* wbf0 = (ushort*)alloc((size_t)Etot * 2 * 2);
  ushort* wbf1 = (ushort*)alloc((size_t)Etot * 2);
  ushort* csrS = (ushort*)alloc((size_t)Etot * 2);

  hipMemsetAsync(ws + zoff0, 0, zbytes, stream);

  // ---- prep: weight transpose+convert ----
  convT_kernel<<<(128 * 256 + 255) / 256, 256, 0, stream>>>(W0, W0T, 128, 256);
  convT_kernel<<<(256 * 128 + 255) / 256, 256, 0, stream>>>(W1, W1T, 256, 128);

  // ---- CSR build (shared by both layers) ----
  const int nblk = (N_NODES + 1023) / 1024;  // 49
  hist_kernel<<<(Etot + 255) / 256, 256, 0, stream>>>(ei, E, Etot, counts, rank);
  scan1_kernel<<<nblk, 1024, 0, stream>>>(counts, partial, bsums, N_NODES);
  scan2_kernel<<<1, 64, 0, stream>>>(bsums, nblk);
  scan3_kernel<<<(N_NODES + 255) / 256, 256, 0, stream>>>(partial, bsums, rowptr, N_NODES);
  scatter_kernel<<<(Etot + 255) / 256, 256, 0, stream>>>(ei, E, Etot, rowptr, rank, csr);

  // ---- layer 0 (x converted fp32->bf16 inside gemm staging) ----
  dim3 g0((N_NODES + 63) / 64, 256 / 64);
  gemm_mfma<2, true><<<g0, 256, 0, stream>>>(x, W0T, h0b, N_NODES, 256, 128,
                                             a_src0, a_dst0, ss0, sd0);
  ew0_kernel<<<(Etot + 255) / 256, 256, 0, stream>>>((const uint2*)csr, ss0, sd0,
                                                     wbf0, csrS, Etot);
  agg0_kernel<<<N_NODES / 4, 256, 0, stream>>>(h0b, wbf0, rowptr, csrS, b0, hEb);

  // ---- layer 1 ----
  dim3 g1((N_NODES + 63) / 64, 128 / 64);
  gemm_mfma<1, false><<<g1, 256, 0, stream>>>(hEb, W1T, h1b, N_NODES, 128, 256,
                                              a_src1, a_dst1, ss1, sd1);
  ew1_kernel<<<(Etot + 255) / 256, 256, 0, stream>>>((const uint2*)csr, ss1, sd1,
                                                     wbf1, Etot);
  agg1_kernel<<<N_NODES / 4, 256, 0, stream>>>(h1b, wbf1, rowptr, csrS, b1,
                                               (const float2*)x, (float2*)out);
}